// Round 1
// baseline (114.034 us; speedup 1.0000x reference)
//
#include <hip/hip_runtime.h>

#define GS   7
#define CCH  490
#define HH   128
#define WW   128
#define NROI 512
#define NB   2

__global__ __launch_bounds__(512, 2) void psroi_fused(
    const float* __restrict__ rois,
    const float* __restrict__ feat,
    const int*   __restrict__ stride_p,
    float*       __restrict__ out)
{
#pragma clang fp contract(off)
    __shared__ float S[HH * WW];   // 64 KB: per-channel inclusive SAT

    const int bc = blockIdx.x;
    const int b  = bc / CCH;
    const int c  = bc - b * CCH;
    const float* f = feat + (size_t)bc * (HH * WW);

    const int tid  = threadIdx.x;
    const int lane = tid & 63;
    const int wave = tid >> 6;     // 0..7, each handles 16 rows

    // ---- Phase 1: load rows + inclusive scan along W (wave shuffle-scan) ----
    for (int r = wave * 16; r < wave * 16 + 16; ++r) {
        float a  = f[r * WW + lane];
        float bv = f[r * WW + 64 + lane];
        float sa = a;
        #pragma unroll
        for (int off = 1; off < 64; off <<= 1) {
            float t = __shfl_up(sa, off, 64);
            if (lane >= off) sa += t;
        }
        float tot = __shfl(sa, 63, 64);
        float sb = bv;
        #pragma unroll
        for (int off = 1; off < 64; off <<= 1) {
            float t = __shfl_up(sb, off, 64);
            if (lane >= off) sb += t;
        }
        sb += tot;
        S[r * WW + lane]      = sa;
        S[r * WW + 64 + lane] = sb;
    }
    __syncthreads();

    // ---- Phase 2: column scan along H: 4 segments x 32 rows + prefix fixup ----
    {
        const int seg = tid >> 7;     // 0..3
        const int col = tid & 127;
        const int r0  = seg * 32;
        float acc = S[r0 * WW + col];
        for (int i = 1; i < 32; ++i) {
            acc += S[(r0 + i) * WW + col];
            S[(r0 + i) * WW + col] = acc;
        }
        __syncthreads();
        const float t0 = S[31 * WW + col];
        const float t1 = S[63 * WW + col];
        const float t2 = S[95 * WW + col];
        __syncthreads();
        float offv = 0.0f;
        if      (seg == 1) offv = t0;
        else if (seg == 2) offv = t0 + t1;
        else if (seg == 3) offv = (t0 + t1) + t2;
        if (seg > 0) {
            for (int i = 0; i < 32; ++i)
                S[(r0 + i) * WW + col] += offv;
        }
    }
    __syncthreads();

    // ---- Phase 3: pooling — thread n handles roi n for this channel ----
    {
        const int n = tid;                    // 512 threads == 512 rois
        const float b_f = rois[n * 5 + 0];
        const int bi = (int)b_f;
        if (bi == b) {
            const float ss = 1.0f / (float)(*stride_p);
            const int d   = c / (GS * GS);
            const int rem = c - d * (GS * GS);
            const int pi  = rem / GS;
            const int pj  = rem - pi * GS;

            float x1 = rois[n * 5 + 1];
            float y1 = rois[n * 5 + 2];
            float x2 = rois[n * 5 + 3];
            float y2 = rois[n * 5 + 4];

            // exact reference op order, fp32, no contraction
            float rsw = rintf(x1) * ss;
            float rsh = rintf(y1) * ss;
            float rew = (rintf(x2) + 1.0f) * ss;
            float reh = (rintf(y2) + 1.0f) * ss;
            float rwv = rew - rsw;
            float rhv = reh - rsh;
            float rwm = rwv * 1.3f;
            float rhm = rhv * 1.3f;
            float swm = (rsw + rew) * 0.5f - rwm * 0.5f;
            float shm = (rsh + reh) * 0.5f - rhm * 0.5f;
            rwm = fmaxf(rwm, 0.1f);
            rhm = fmaxf(rhm, 0.1f);
            float bin_h = rhm / 7.0f;
            float bin_w = rwm / 7.0f;
            float dh = bin_h * 0.25f;   // bin_h * 0.5 * 0.5 (exact pow2 mults)
            float dw = bin_w * 0.25f;

            float gi = (float)pi;
            float gj = (float)pj;
            int hs  = (int)fminf(fmaxf(floorf(shm + gi * bin_h - dh),          0.0f), 128.0f);
            int he  = (int)fminf(fmaxf(ceilf (shm + (gi + 1.0f) * bin_h + dh), 0.0f), 128.0f);
            int ws_ = (int)fminf(fmaxf(floorf(swm + gj * bin_w - dw),          0.0f), 128.0f);
            int we  = (int)fminf(fmaxf(ceilf (swm + (gj + 1.0f) * bin_w + dw), 0.0f), 128.0f);

            int area = (he - hs) * (we - ws_);
            float A  = (he > 0 && we  > 0) ? S[(he - 1) * WW + (we  - 1)] : 0.0f;
            float Bv = (hs > 0 && we  > 0) ? S[(hs - 1) * WW + (we  - 1)] : 0.0f;
            float Cv = (he > 0 && ws_ > 0) ? S[(he - 1) * WW + (ws_ - 1)] : 0.0f;
            float Dv = (hs > 0 && ws_ > 0) ? S[(hs - 1) * WW + (ws_ - 1)] : 0.0f;
            float total = ((A - Bv) - Cv) + Dv;   // reference order
            out[(size_t)n * CCH + c] = (area > 0) ? (total / (float)area) : 0.0f;
        }
    }
}

extern "C" void kernel_launch(void* const* d_in, const int* in_sizes, int n_in,
                              void* d_out, int out_size, void* d_ws, size_t ws_size,
                              hipStream_t stream)
{
    const float* rois     = (const float*)d_in[0];
    const float* feat     = (const float*)d_in[1];
    const int*   stride_p = (const int*)d_in[2];
    float*       out      = (float*)d_out;

    dim3 grid(NB * CCH);   // one workgroup per (batch, channel)
    dim3 block(512);
    hipLaunchKernelGGL(psroi_fused, grid, block, 0, stream, rois, feat, stride_p, out);
}

// Round 2
// 99.040 us; speedup vs baseline: 1.1514x; 1.1514x over previous
//
#include <hip/hip_runtime.h>

#define GS   7
#define CCH  490
#define HH   128
#define WW   128
#define NB   2

// XOR-swizzled LDS index at float4 granularity: keeps b128 alignment,
// spreads banks so phase-B row-reads are conflict-free and phase-A
// column-writes are 2-way (free).
__device__ __forceinline__ int sidx(int r, int c) {
    return r * WW + ((((c >> 2) ^ (r & 31)) << 2) | (c & 3));
}

__global__ __launch_bounds__(512, 4) void psroi_fused(
    const float* __restrict__ rois,
    const float* __restrict__ feat,
    const int*   __restrict__ stride_p,
    float*       __restrict__ out)
{
#pragma clang fp contract(off)
    __shared__ float S[HH * WW];   // exactly 64 KB

    const int bc = blockIdx.x;
    const int b  = bc / CCH;
    const int c  = bc - b * CCH;
    const float* __restrict__ f = feat + (size_t)bc * (HH * WW);
    const int tid = threadIdx.x;

    // ---- Phase A: cumsum over H (reference inner axis). thread = (col, 32-row seg)
    {
        const int col = tid & 127;      // wave = 64 consecutive cols, same seg
        const int seg = tid >> 7;       // 0..3
        const int r0  = seg * 32;

        float v[32];
        #pragma unroll
        for (int i = 0; i < 32; ++i)    // coalesced: 256B per wave-load
            v[i] = f[(r0 + i) * WW + col];
        #pragma unroll
        for (int i = 1; i < 32; ++i)    // serial register scan
            v[i] += v[i - 1];

        S[seg * WW + col] = v[31];      // temp seg totals (scratch, pre-final)
        __syncthreads();
        float off = 0.0f;               // wave-uniform branches (seg uniform per wave)
        if (seg > 0) off += S[0 * WW + col];
        if (seg > 1) off += S[1 * WW + col];
        if (seg > 2) off += S[2 * WW + col];
        __syncthreads();

        #pragma unroll
        for (int i = 0; i < 32; ++i)    // final col-prefixes, swizzled, 2-way banks
            S[sidx(r0 + i, col)] = v[i] + off;
    }
    __syncthreads();

    // ---- Phase B: cumsum over W. thread = (row, 32-col seg); quads share a row.
    {
        const int row = tid >> 2;       // wave = 16 rows x 4 col-segs
        const int ws_ = tid & 3;
        const int sw  = row & 31;

        float u[32];
        #pragma unroll
        for (int i = 0; i < 8; ++i) {   // 8x ds_read_b128, conflict-free
            const float4 q = *(const float4*)&S[row * WW + (((ws_ * 8 + i) ^ sw) << 2)];
            u[4 * i + 0] = q.x; u[4 * i + 1] = q.y;
            u[4 * i + 2] = q.z; u[4 * i + 3] = q.w;
        }
        #pragma unroll
        for (int i = 1; i < 32; ++i)
            u[i] += u[i - 1];

        const float tot = u[31];        // cross-seg fixup: 3 shuffles within quad
        const float t1 = __shfl_up(tot, 1, 64);
        const float t2 = __shfl_up(tot, 2, 64);
        const float t3 = __shfl_up(tot, 3, 64);
        float off = 0.0f;
        if (ws_ > 0) off += t1;
        if (ws_ > 1) off += t2;
        if (ws_ > 2) off += t3;

        #pragma unroll
        for (int i = 0; i < 8; ++i) {   // 8x ds_write_b128, in-place, conflict-free
            float4 q;
            q.x = u[4 * i + 0] + off; q.y = u[4 * i + 1] + off;
            q.z = u[4 * i + 2] + off; q.w = u[4 * i + 3] + off;
            *(float4*)&S[row * WW + (((ws_ * 8 + i) ^ sw) << 2)] = q;
        }
    }
    __syncthreads();

    // ---- Phase 3: pooling — thread n handles roi n for this channel ----
    {
        const int n = tid;              // 512 threads == 512 rois
        const float b_f = rois[n * 5 + 0];
        const int bi = (int)b_f;
        if (bi == b) {
            const float ss = 1.0f / (float)(*stride_p);
            const int d   = c / (GS * GS);
            const int rem = c - d * (GS * GS);
            const int pi  = rem / GS;
            const int pj  = rem - pi * GS;

            const float x1 = rois[n * 5 + 1];
            const float y1 = rois[n * 5 + 2];
            const float x2 = rois[n * 5 + 3];
            const float y2 = rois[n * 5 + 4];

            // exact reference op order, fp32, no contraction
            float rsw = rintf(x1) * ss;
            float rsh = rintf(y1) * ss;
            float rew = (rintf(x2) + 1.0f) * ss;
            float reh = (rintf(y2) + 1.0f) * ss;
            float rwv = rew - rsw;
            float rhv = reh - rsh;
            float rwm = rwv * 1.3f;
            float rhm = rhv * 1.3f;
            float swm = (rsw + rew) * 0.5f - rwm * 0.5f;
            float shm = (rsh + reh) * 0.5f - rhm * 0.5f;
            rwm = fmaxf(rwm, 0.1f);
            rhm = fmaxf(rhm, 0.1f);
            float bin_h = rhm / 7.0f;
            float bin_w = rwm / 7.0f;
            float dh = bin_h * 0.25f;
            float dw = bin_w * 0.25f;

            const float gi = (float)pi;
            const float gj = (float)pj;
            const int hs  = (int)fminf(fmaxf(floorf(shm + gi * bin_h - dh),          0.0f), 128.0f);
            const int he  = (int)fminf(fmaxf(ceilf (shm + (gi + 1.0f) * bin_h + dh), 0.0f), 128.0f);
            const int ws2 = (int)fminf(fmaxf(floorf(swm + gj * bin_w - dw),          0.0f), 128.0f);
            const int we  = (int)fminf(fmaxf(ceilf (swm + (gj + 1.0f) * bin_w + dw), 0.0f), 128.0f);

            const int area = (he - hs) * (we - ws2);
            const float A  = (he > 0 && we  > 0) ? S[sidx(he - 1, we  - 1)] : 0.0f;
            const float Bv = (hs > 0 && we  > 0) ? S[sidx(hs - 1, we  - 1)] : 0.0f;
            const float Cv = (he > 0 && ws2 > 0) ? S[sidx(he - 1, ws2 - 1)] : 0.0f;
            const float Dv = (hs > 0 && ws2 > 0) ? S[sidx(hs - 1, ws2 - 1)] : 0.0f;
            const float total = ((A - Bv) - Cv) + Dv;   // reference order
            out[(size_t)n * CCH + c] = (area > 0) ? (total / (float)area) : 0.0f;
        }
    }
}

extern "C" void kernel_launch(void* const* d_in, const int* in_sizes, int n_in,
                              void* d_out, int out_size, void* d_ws, size_t ws_size,
                              hipStream_t stream)
{
    const float* rois     = (const float*)d_in[0];
    const float* feat     = (const float*)d_in[1];
    const int*   stride_p = (const int*)d_in[2];
    float*       out      = (float*)d_out;

    dim3 grid(NB * CCH);   // one workgroup per (batch, channel)
    dim3 block(512);
    hipLaunchKernelGGL(psroi_fused, grid, block, 0, stream, rois, feat, stride_p, out);
}

// Round 3
// 98.085 us; speedup vs baseline: 1.1626x; 1.0097x over previous
//
#include <hip/hip_runtime.h>

#define GS   7
#define CCH  490
#define HH   128
#define WW   128
#define LDW  132        // padded LDS row stride (floats): +4 keeps b128 16B-aligned,
                        // gives conflict-free b128 row access and free b32 col access
#define NB   2

__global__ __launch_bounds__(512, 4) void psroi_fused(
    const float* __restrict__ rois,
    const float* __restrict__ feat,
    const int*   __restrict__ stride_p,
    float*       __restrict__ out)
{
#pragma clang fp contract(off)
    __shared__ float S[HH * LDW];   // 67,584 B -> 2 blocks/CU

    const int bc = blockIdx.x;
    const int b  = bc / CCH;
    const int c  = bc - b * CCH;
    const float* __restrict__ f = feat + (size_t)bc * (HH * WW);
    const int tid = threadIdx.x;

    // ---- Phase A: cumsum over H (reference inner axis). thread = (col, 32-row seg)
    {
        const int col = tid & 127;      // wave = 64 consecutive cols, same seg
        const int seg = tid >> 7;       // 0..3
        const int r0  = seg * 32;

        float v[32];
        const float* fp = f + r0 * WW + col;
        #pragma unroll
        for (int i = 0; i < 32; ++i)    // coalesced: 256B per wave-load
            v[i] = fp[i * WW];
        #pragma unroll
        for (int i = 1; i < 32; ++i)    // serial register scan
            v[i] += v[i - 1];

        // seg-total exchange through S rows 0..3 (overwritten by final writes later)
        S[seg * LDW + col] = v[31];
        __syncthreads();
        float off = 0.0f;               // seg uniform per wave -> uniform branches
        if (seg > 0) off += S[0 * LDW + col];
        if (seg > 1) off += S[1 * LDW + col];
        if (seg > 2) off += S[2 * LDW + col];
        __syncthreads();

        float* sp = &S[r0 * LDW + col];
        #pragma unroll
        for (int i = 0; i < 32; ++i)    // imm-offset ds_write_b32, 2-way banks (free)
            sp[i * LDW] = v[i] + off;
    }
    __syncthreads();

    // ---- Phase B: cumsum over W. thread = (row, 32-col seg); quads share a row.
    {
        const int row = tid >> 2;       // wave = 16 rows x 4 col-segs
        const int ws_ = tid & 3;
        float* rp = &S[row * LDW + ws_ * 32];

        float u[32];
        #pragma unroll
        for (int i = 0; i < 8; ++i) {   // 8x ds_read_b128, imm offsets, conflict-free
            const float4 q = *(const float4*)&rp[i * 4];
            u[4 * i + 0] = q.x; u[4 * i + 1] = q.y;
            u[4 * i + 2] = q.z; u[4 * i + 3] = q.w;
        }
        #pragma unroll
        for (int i = 1; i < 32; ++i)
            u[i] += u[i - 1];

        const float tot = u[31];        // cross-seg fixup: 3 shuffles within quad
        const float t1 = __shfl_up(tot, 1, 64);
        const float t2 = __shfl_up(tot, 2, 64);
        const float t3 = __shfl_up(tot, 3, 64);
        float off = 0.0f;
        if (ws_ > 0) off += t1;
        if (ws_ > 1) off += t2;
        if (ws_ > 2) off += t3;

        #pragma unroll
        for (int i = 0; i < 8; ++i) {   // 8x ds_write_b128 in place
            float4 q;
            q.x = u[4 * i + 0] + off; q.y = u[4 * i + 1] + off;
            q.z = u[4 * i + 2] + off; q.w = u[4 * i + 3] + off;
            *(float4*)&rp[i * 4] = q;
        }
    }
    __syncthreads();

    // ---- Phase 3: pooling — thread n handles roi n for this channel ----
    {
        const int n = tid;              // 512 threads == 512 rois
        const float b_f = rois[n * 5 + 0];
        const int bi = (int)b_f;
        if (bi == b) {
            const float ss = 1.0f / (float)(*stride_p);
            const int d   = c / (GS * GS);
            const int rem = c - d * (GS * GS);
            const int pi  = rem / GS;
            const int pj  = rem - pi * GS;

            const float x1 = rois[n * 5 + 1];
            const float y1 = rois[n * 5 + 2];
            const float x2 = rois[n * 5 + 3];
            const float y2 = rois[n * 5 + 4];

            // exact reference op order, fp32, no contraction
            float rsw = rintf(x1) * ss;
            float rsh = rintf(y1) * ss;
            float rew = (rintf(x2) + 1.0f) * ss;
            float reh = (rintf(y2) + 1.0f) * ss;
            float rwv = rew - rsw;
            float rhv = reh - rsh;
            float rwm = rwv * 1.3f;
            float rhm = rhv * 1.3f;
            float swm = (rsw + rew) * 0.5f - rwm * 0.5f;
            float shm = (rsh + reh) * 0.5f - rhm * 0.5f;
            rwm = fmaxf(rwm, 0.1f);
            rhm = fmaxf(rhm, 0.1f);
            float bin_h = rhm / 7.0f;
            float bin_w = rwm / 7.0f;
            float dh = bin_h * 0.25f;
            float dw = bin_w * 0.25f;

            const float gi = (float)pi;
            const float gj = (float)pj;
            const int hs  = (int)fminf(fmaxf(floorf(shm + gi * bin_h - dh),          0.0f), 128.0f);
            const int he  = (int)fminf(fmaxf(ceilf (shm + (gi + 1.0f) * bin_h + dh), 0.0f), 128.0f);
            const int ws2 = (int)fminf(fmaxf(floorf(swm + gj * bin_w - dw),          0.0f), 128.0f);
            const int we  = (int)fminf(fmaxf(ceilf (swm + (gj + 1.0f) * bin_w + dw), 0.0f), 128.0f);

            const int area = (he - hs) * (we - ws2);
            const float A  = (he > 0 && we  > 0) ? S[(he - 1) * LDW + (we  - 1)] : 0.0f;
            const float Bv = (hs > 0 && we  > 0) ? S[(hs - 1) * LDW + (we  - 1)] : 0.0f;
            const float Cv = (he > 0 && ws2 > 0) ? S[(he - 1) * LDW + (ws2 - 1)] : 0.0f;
            const float Dv = (hs > 0 && ws2 > 0) ? S[(hs - 1) * LDW + (ws2 - 1)] : 0.0f;
            const float total = ((A - Bv) - Cv) + Dv;   // reference order
            out[(size_t)n * CCH + c] = (area > 0) ? (total / (float)area) : 0.0f;
        }
    }
}

extern "C" void kernel_launch(void* const* d_in, const int* in_sizes, int n_in,
                              void* d_out, int out_size, void* d_ws, size_t ws_size,
                              hipStream_t stream)
{
    const float* rois     = (const float*)d_in[0];
    const float* feat     = (const float*)d_in[1];
    const int*   stride_p = (const int*)d_in[2];
    float*       out      = (float*)d_out;

    dim3 grid(NB * CCH);   // one workgroup per (batch, channel)
    dim3 block(512);
    hipLaunchKernelGGL(psroi_fused, grid, block, 0, stream, rois, feat, stride_p, out);
}